// Round 2
// baseline (613.476 us; speedup 1.0000x reference)
//
#include <hip/hip_runtime.h>
#include <math.h>

#define EPSF 1e-6f
#define TCLIP (1.0f - 1e-5f)
#define NPTS 16384
#define DDIM 256
#define NBLK 128
#define PPB 128   // points per block
#define PPW 32    // points per wave (4 waves/block)
#define PSTR 260  // partial stride: 256 vec + 1 scalar + pad
#define FRECHET_ITERS_N 10

// ws float layout:
// [0]                      grid-barrier counter (unsigned, monotonic)
// [64, 64+NBLK*PSTR)       partial buffer A
// [.., +NBLK*PSTR)         partial buffer B
#define WS_BAR 0
#define WS_PA 64
#define WS_PB (WS_PA + NBLK * PSTR)

__device__ __forceinline__ float block_sum256(float v) {
    __shared__ float s_bs[4];
    #pragma unroll
    for (int off = 32; off; off >>= 1) v += __shfl_xor(v, off);
    const int w = threadIdx.x >> 6, l = threadIdx.x & 63;
    __syncthreads();                 // protect s_bs reuse across calls
    if (l == 0) s_bs[w] = v;
    __syncthreads();
    return s_bs[0] + s_bs[1] + s_bs[2] + s_bs[3];
}

// monotonic grid barrier: all NBLK blocks co-resident (cooperative launch)
__device__ __forceinline__ void gbar(unsigned* cnt, unsigned target) {
    __syncthreads();
    if (threadIdx.x == 0) {
        __hip_atomic_fetch_add(cnt, 1u, __ATOMIC_ACQ_REL, __HIP_MEMORY_SCOPE_AGENT);
        while (__hip_atomic_load(cnt, __ATOMIC_ACQUIRE, __HIP_MEMORY_SCOPE_AGENT) < target) {
            __builtin_amdgcn_s_sleep(2);
        }
    }
    __syncthreads();
}

__global__ void init_bar(float* ws) { ((unsigned*)(ws + WS_BAR))[0] = 0u; }

__global__ __launch_bounds__(256, 1) void rbn_fused(
    const float* __restrict__ x, const float* __restrict__ Kp,
    const float* __restrict__ mean_param, const float* __restrict__ var_param,
    float* __restrict__ out, float* __restrict__ ws)
{
    const float c = -Kp[0];
    const float sc = sqrtf(c);
    const int t = threadIdx.x, lane = t & 63, wv = t >> 6;
    const int b = blockIdx.x;
    const int pw0 = b * PPB + wv * PPW;

    unsigned* bar = (unsigned*)(ws + WS_BAR);
    float* PA = ws + WS_PA;
    float* PB = ws + WS_PB;

    __shared__ float mu_s[DDIM];
    __shared__ float om_s[DDIM];
    __shared__ float red[4 * DDIM];
    __shared__ float redA[4];

    unsigned barno = 0;

    // block-level vector+scalar reduce of per-wave partials, store to global buf
    auto vec_reduce_store = [&](float4 a4, float asc, float* dst) {
        __syncthreads();
        ((float4*)(red + wv * DDIM))[lane] = a4;
        if (lane == 0) redA[wv] = asc;
        __syncthreads();
        dst[b * PSTR + t] = red[t] + red[DDIM + t] + red[2 * DDIM + t] + red[3 * DDIM + t];
        if (t == 0) dst[b * PSTR + DDIM] = redA[0] + redA[1] + redA[2] + redA[3];
    };

    // ---- Phase 0: om = exp0(mean_param), redundant per block ----
    {
        float u = mean_param[t];
        float un2 = block_sum256(u * u);
        float un = sqrtf(fmaxf(un2, EPSF));
        om_s[t] = tanhf(sc * un) * u / (sc * un);
    }
    const float om2 = block_sum256(om_s[t] * om_s[t]);

    // ---- Phase 0b: Euclidean mean partial ----
    {
        float4 a = make_float4(0.f, 0.f, 0.f, 0.f);
        for (int i = 0; i < PPW; ++i) {
            float4 x4 = ((const float4*)x)[(pw0 + i) * 64 + lane];
            a.x += x4.x; a.y += x4.y; a.z += x4.z; a.w += x4.w;
        }
        vec_reduce_store(a, 0.f, PA);
    }
    gbar(bar, ++barno * NBLK);

    // ---- init mu (redundant per block) ----
    {
        float s = 0.f;
        for (int bb = 0; bb < NBLK; ++bb) s += PA[bb * PSTR + t];
        float m = s * (1.f / NPTS);
        float mn2 = block_sum256(m * m);
        float mn = sqrtf(fmaxf(mn2, EPSF));
        float maxn = (1.f - 1e-3f) / sc;
        float f = fminf(1.f, maxn / mn);
        mu_s[t] = m * f;
    }
    float mu2 = block_sum256(mu_s[t] * mu_s[t]);

    // ---- Karcher iterations ----
    for (int it = 0; it < FRECHET_ITERS_N; ++it) {
        float* buf = (it & 1) ? PA : PB;
        float4 mu4 = ((const float4*)mu_s)[lane];
        float4 a = make_float4(0.f, 0.f, 0.f, 0.f);
        float accA = 0.f;
        for (int i = 0; i < PPW; ++i) {
            float4 x4 = ((const float4*)x)[(pw0 + i) * 64 + lane];
            float y2 = x4.x * x4.x + x4.y * x4.y + x4.z * x4.z + x4.w * x4.w;
            float d  = mu4.x * x4.x + mu4.y * x4.y + mu4.z * x4.z + mu4.w * x4.w;
            #pragma unroll
            for (int off = 32; off; off >>= 1) {
                y2 += __shfl_xor(y2, off);
                d  += __shfl_xor(d, off);
            }
            float P = 1.f - 2.f * c * d;
            float den = fmaxf(P + c * c * mu2 * y2, EPSF);
            float A = -(P + c * y2) / den;
            float B = (1.f - c * mu2) / den;
            float mn2 = fmaxf(A * A * mu2 + 2.f * A * B * d + B * B * y2, EPSF);
            float mn = sqrtf(mn2);
            float tt = atanhf(fminf(sc * mn, TCLIP));
            float s = (fmaxf(1.f - c * mu2, EPSF) / sc) * tt / mn;
            float w = s * B;
            a.x += w * x4.x; a.y += w * x4.y; a.z += w * x4.z; a.w += w * x4.w;
            accA += s * A;
        }
        vec_reduce_store(a, accA, buf);
        gbar(bar, ++barno * NBLK);

        // finalize: mu <- expmap(mu, g), redundant per block
        float sv = 0.f, sA = 0.f;
        for (int bb = 0; bb < NBLK; ++bb) {
            sv += buf[bb * PSTR + t];
            sA += buf[bb * PSTR + DDIM];
        }
        float mu = mu_s[t];
        float g = sv * (1.f / NPTS) + (sA * (1.f / NPTS)) * mu;
        float gn2 = block_sum256(g * g);
        float mg  = block_sum256(mu * g);
        float un = sqrtf(fmaxf(gn2, EPSF));
        float lam = 2.f / fmaxf(1.f - c * mu2, EPSF);
        float k = tanhf(sc * lam * un * 0.5f) / (sc * un);
        float sec = k * g;
        float ms = k * mg;
        float s2 = k * k * gn2;
        float aa = 1.f + 2.f * c * ms + c * s2;
        float bb2 = 1.f - c * mu2;
        float den = fmaxf(1.f + 2.f * c * ms + c * c * mu2 * s2, EPSF);
        float nmu = (aa * mu + bb2 * sec) / den;
        mu_s[t] = nmu;
        mu2 = block_sum256(nmu * nmu);   // internal syncs also fence the mu_s write
    }

    // ---- variance pass ----
    {
        float* vbuf = (FRECHET_ITERS_N & 1) ? PA : PB;
        float4 mu4 = ((const float4*)mu_s)[lane];
        float accv = 0.f;
        for (int i = 0; i < PPW; ++i) {
            float4 x4 = ((const float4*)x)[(pw0 + i) * 64 + lane];
            float y2 = x4.x * x4.x + x4.y * x4.y + x4.z * x4.z + x4.w * x4.w;
            float d  = mu4.x * x4.x + mu4.y * x4.y + mu4.z * x4.z + mu4.w * x4.w;
            #pragma unroll
            for (int off = 32; off; off >>= 1) {
                y2 += __shfl_xor(y2, off);
                d  += __shfl_xor(d, off);
            }
            float P = 1.f - 2.f * c * d;
            float den = fmaxf(P + c * c * mu2 * y2, EPSF);
            float A = -(P + c * y2) / den;
            float B = (1.f - c * mu2) / den;
            float mn2 = fmaxf(A * A * mu2 + 2.f * A * B * d + B * B * y2, EPSF);
            float mn = sqrtf(mn2);
            float tt = atanhf(fminf(sc * mn, TCLIP));
            float dd = (2.f / sc) * tt;
            accv += dd * dd;
        }
        __syncthreads();
        if (lane == 0) redA[wv] = accv;   // accv is lane-uniform
        __syncthreads();
        if (t == 0) vbuf[b * PSTR + DDIM] = redA[0] + redA[1] + redA[2] + redA[3];
        gbar(bar, ++barno * NBLK);

        float sA = 0.f;
        for (int bb = 0; bb < NBLK; ++bb) sA += vbuf[bb * PSTR + DDIM];
        float var = sA * (1.f / NPTS);
        float gamma = sqrtf(var_param[0] / (var + 1e-6f));

        // transport/output scalars, redundant & thread-uniform
        float omu = block_sum256(om_s[t] * mu_s[t]);
        float Amu = fmaxf(1.f - c * mu2, EPSF);
        float Aom = fmaxf(1.f - c * om2, EPSF);
        float ratio = Aom / Amu;           // lam_mu / lam_om
        float aq = 1.f - 2.f * c * omu + c * mu2;
        float bq = 1.f - c * om2;
        float dq = fmaxf(1.f - 2.f * c * omu + c * c * om2 * mu2, EPSF);
        float qo = aq / dq, qm = -bq / dq;
        float q2 = qo * qo * om2 + 2.f * qo * qm * omu + qm * qm * mu2;
        float lam_om = 2.f / Aom;

        // ---- output pass (fully local) ----
        float4 om4 = ((const float4*)om_s)[lane];
        float4 mmu4 = ((const float4*)mu_s)[lane];

        auto dotOm = [&](float po, float pm, float px, float e, float d) {
            return po * om2 + pm * omu + px * e;
        };
        auto dotMu = [&](float po, float pm, float px, float e, float d) {
            return po * omu + pm * mu2 + px * d;
        };

        for (int i = 0; i < PPW; ++i) {
            float4 x4 = ((const float4*)x)[(pw0 + i) * 64 + lane];
            float y2 = x4.x * x4.x + x4.y * x4.y + x4.z * x4.z + x4.w * x4.w;
            float d  = mmu4.x * x4.x + mmu4.y * x4.y + mmu4.z * x4.z + mmu4.w * x4.w;
            float e  = om4.x * x4.x + om4.y * x4.y + om4.z * x4.z + om4.w * x4.w;
            #pragma unroll
            for (int off = 32; off; off >>= 1) {
                y2 += __shfl_xor(y2, off);
                d  += __shfl_xor(d, off);
                e  += __shfl_xor(e, off);
            }
            auto sqn3 = [&](float po, float pm, float px) {
                return po * po * om2 + pm * pm * mu2 + px * px * y2
                     + 2.f * (po * pm * omu + po * px * e + pm * px * d);
            };

            // u = logmap(mu, x_i) = Um*mu + Ux*x_i
            float P = 1.f - 2.f * c * d;
            float den0 = fmaxf(P + c * c * mu2 * y2, EPSF);
            float A = -(P + c * y2) / den0;
            float B = (1.f - c * mu2) / den0;
            float mn2 = fmaxf(A * A * mu2 + 2.f * A * B * d + B * B * y2, EPSF);
            float mn = sqrtf(mn2);
            float tt = atanhf(fminf(sc * mn, TCLIP));
            float s = (fmaxf(1.f - c * mu2, EPSF) / sc) * tt / mn;
            float Um = s * A, Ux = s * B;

            // h1 = mobius_add(-mu, u)
            float xy1 = -dotMu(0.f, Um, Ux, e, d);
            float Y21 = sqn3(0.f, Um, Ux);
            float a1 = 1.f + 2.f * c * xy1 + c * Y21;
            float b1 = 1.f - c * mu2;
            float dn1 = fmaxf(1.f + 2.f * c * xy1 + c * c * mu2 * Y21, EPSF);
            float h1m = (-a1 + b1 * Um) / dn1;
            float h1x = (b1 * Ux) / dn1;

            // h2 = mobius_add(om, h1)
            float xy2 = dotOm(0.f, h1m, h1x, e, d);
            float Y22 = sqn3(0.f, h1m, h1x);
            float a2 = 1.f + 2.f * c * xy2 + c * Y22;
            float b2 = 1.f - c * om2;
            float dn2 = fmaxf(1.f + 2.f * c * xy2 + c * c * om2 * Y22, EPSF);
            float h2o = a2 / dn2;
            float h2m = (b2 * h1m) / dn2;
            float h2x = (b2 * h1x) / dn2;

            // g2 = mobius_add(-q, h2), q = qo*om + qm*mu
            float xy3 = -(qo * dotOm(h2o, h2m, h2x, e, d) + qm * dotMu(h2o, h2m, h2x, e, d));
            float Y23 = sqn3(h2o, h2m, h2x);
            float a3 = 1.f + 2.f * c * xy3 + c * Y23;
            float b3 = 1.f - c * q2;
            float dn3 = fmaxf(1.f + 2.f * c * xy3 + c * c * q2 * Y23, EPSF);
            float g2o = (-a3 * qo + b3 * h2o) / dn3;
            float g2m = (-a3 * qm + b3 * h2m) / dn3;
            float g2x = (b3 * h2x) / dn3;

            // L = ratio*gamma*g2 ; out = expmap(om, L)
            float k1 = ratio * gamma;
            float Lo = k1 * g2o, Lm = k1 * g2m, Lx = k1 * g2x;
            float un2 = sqn3(Lo, Lm, Lx);
            float un = sqrtf(fmaxf(un2, EPSF));
            float coef = tanhf(sc * lam_om * un * 0.5f) / (sc * un);
            float So = coef * Lo, Sm = coef * Lm, Sx = coef * Lx;
            float xy4 = dotOm(So, Sm, Sx, e, d);
            float Y24 = coef * coef * un2;
            float a4 = 1.f + 2.f * c * xy4 + c * Y24;
            float b4 = 1.f - c * om2;
            float dn4 = fmaxf(1.f + 2.f * c * xy4 + c * c * om2 * Y24, EPSF);
            float fo = (a4 + b4 * So) / dn4;
            float fm = (b4 * Sm) / dn4;
            float fx = (b4 * Sx) / dn4;

            float4 o4;
            o4.x = fo * om4.x + fm * mmu4.x + fx * x4.x;
            o4.y = fo * om4.y + fm * mmu4.y + fx * x4.y;
            o4.z = fo * om4.z + fm * mmu4.z + fx * x4.z;
            o4.w = fo * om4.w + fm * mmu4.w + fx * x4.w;
            ((float4*)out)[(pw0 + i) * 64 + lane] = o4;
        }
    }
}

extern "C" void kernel_launch(void* const* d_in, const int* in_sizes, int n_in,
                              void* d_out, int out_size, void* d_ws, size_t ws_size,
                              hipStream_t stream) {
    const float* x = (const float*)d_in[0];
    const float* K = (const float*)d_in[1];
    const float* mean_param = (const float*)d_in[2];
    const float* var_param = (const float*)d_in[3];
    float* out = (float*)d_out;
    float* ws = (float*)d_ws;

    init_bar<<<1, 1, 0, stream>>>(ws);
    void* args[] = {(void*)&x, (void*)&K, (void*)&mean_param, (void*)&var_param,
                    (void*)&out, (void*)&ws};
    hipLaunchCooperativeKernel((const void*)rbn_fused, dim3(NBLK), dim3(256),
                               args, 0, stream);
}

// Round 3
// 565.777 us; speedup vs baseline: 1.0843x; 1.0843x over previous
//
#include <hip/hip_runtime.h>
#include <math.h>

#define EPSF 1e-6f
#define TCLIP (1.0f - 1e-5f)
#define NPTS 16384
#define DDIM 256
#define NBLK 128
#define NTHR 1024
#define PPB 128   // points per block
#define NWAVE 16
#define PPW 8     // points per wave in dot-style passes
#define PSTR 260  // partial stride: 256 vec + 1 scalar + pad
#define FRECHET_ITERS_N 10

// ws float layout:
// [0]                    grid-barrier counter (unsigned, monotonic)
// [64, 64+NBLK*PSTR)     partial buffer A
// [.., +NBLK*PSTR)       partial buffer B
#define WS_BAR 0
#define WS_PA 64
#define WS_PB (WS_PA + NBLK * PSTR)

__device__ __forceinline__ float block_sum(float v) {
    __shared__ float s_bs[NWAVE];
    #pragma unroll
    for (int off = 32; off; off >>= 1) v += __shfl_xor(v, off);
    const int w = threadIdx.x >> 6, l = threadIdx.x & 63;
    __syncthreads();                 // protect s_bs reuse across calls
    if (l == 0) s_bs[w] = v;
    __syncthreads();
    float s = 0.f;
    #pragma unroll
    for (int i = 0; i < NWAVE; ++i) s += s_bs[i];
    return s;
}

// monotonic grid barrier: all NBLK blocks co-resident (cooperative launch)
__device__ __forceinline__ void gbar(unsigned* cnt, unsigned target) {
    __syncthreads();
    if (threadIdx.x == 0) {
        __hip_atomic_fetch_add(cnt, 1u, __ATOMIC_ACQ_REL, __HIP_MEMORY_SCOPE_AGENT);
        while (__hip_atomic_load(cnt, __ATOMIC_ACQUIRE, __HIP_MEMORY_SCOPE_AGENT) < target) {
            __builtin_amdgcn_s_sleep(2);
        }
    }
    __syncthreads();
}

__global__ void init_bar(float* ws) { ((unsigned*)(ws + WS_BAR))[0] = 0u; }

__global__ __launch_bounds__(NTHR, 1) void rbn_fused(
    const float* __restrict__ x, const float* __restrict__ Kp,
    const float* __restrict__ mean_param, const float* __restrict__ var_param,
    float* __restrict__ out, float* __restrict__ ws)
{
    const float c = -Kp[0];
    const float sc = sqrtf(c);
    const int t = threadIdx.x, lane = t & 63, wv = t >> 6;
    const int b = blockIdx.x;
    const int p0 = b * PPB;
    const float4* xr = ((const float4*)x) + p0 * 64;

    unsigned* bar = (unsigned*)(ws + WS_BAR);
    float* PA = ws + WS_PA;
    float* PB = ws + WS_PB;

    __shared__ float mu_s[DDIM], om_s[DDIM];
    __shared__ float dpart[PPB * 65];   // padded: stride 65 breaks bank aliasing
    __shared__ float dqr[PPB * 9];      // padded: stride 9
    __shared__ float y2_s[PPB], e_s[PPB], d_s[PPB], w_s[PPB], sA_s[PPB], fx_s[PPB];
    __shared__ float pseg[4 * DDIM];

    unsigned barno = 0;

    // batched per-point dot: dst[pl] = <x_pl, v> (or ||x_pl||^2 if self)
    // per-lane 4-wide partials -> padded LDS tree, all 1024 threads reduce
    auto dot_rows = [&](float4 v4, float* dst, bool self) {
        #pragma unroll
        for (int i = 0; i < PPW; ++i) {
            int pl = wv * PPW + i;
            float4 xv = xr[pl * 64 + lane];
            float4 u4 = self ? xv : v4;
            dpart[pl * 65 + lane] = xv.x * u4.x + xv.y * u4.y + xv.z * u4.z + xv.w * u4.w;
        }
        __syncthreads();
        {
            int pl = t & 127, q = t >> 7;   // 8 threads per point
            float s = 0.f;
            #pragma unroll
            for (int j = 0; j < 8; ++j) s += dpart[pl * 65 + q * 8 + j];
            dqr[pl * 9 + q] = s;
        }
        __syncthreads();
        if (t < PPB) {
            float s = 0.f;
            #pragma unroll
            for (int j = 0; j < 8; ++j) s += dqr[t * 9 + j];
            dst[t] = s;
        }
        __syncthreads();
    };

    // ---- om = exp0(mean_param), redundant per block ----
    {
        float u = (t < DDIM) ? mean_param[t] : 0.f;
        float un2 = block_sum(u * u);
        float un = sqrtf(fmaxf(un2, EPSF));
        if (t < DDIM) om_s[t] = tanhf(sc * un) * u / (sc * un);
    }
    float om2;
    { float v = (t < DDIM) ? om_s[t] * om_s[t] : 0.f; om2 = block_sum(v); }

    // ---- precompute y2 and e = <om, x> (no barrier needed) ----
    dot_rows(make_float4(0.f, 0.f, 0.f, 0.f), y2_s, true);
    {
        float4 om4 = ((const float4*)om_s)[lane];
        dot_rows(om4, e_s, false);
    }

    // ---- Euclidean mean partial (transposed, coalesced) ----
    {
        const int dim = t & 255, seg = t >> 8;
        float acc = 0.f;
        for (int ii = 0; ii < 32; ++ii) {
            int i = seg * 32 + ii;
            acc += x[(p0 + i) * DDIM + dim];
        }
        pseg[seg * DDIM + dim] = acc;
        __syncthreads();
        if (t < DDIM)
            PA[b * PSTR + t] = pseg[t] + pseg[DDIM + t] + pseg[2 * DDIM + t] + pseg[3 * DDIM + t];
    }
    gbar(bar, ++barno * NBLK);

    // ---- init mu (redundant per block) ----
    float mu2;
    {
        float s = 0.f;
        if (t < DDIM) for (int bb = 0; bb < NBLK; ++bb) s += PA[bb * PSTR + t];
        float m = s * (1.f / NPTS);
        float mn2 = block_sum(m * m);
        float mn = sqrtf(fmaxf(mn2, EPSF));
        float maxn = (1.f - 1e-3f) / sc;
        float f = fminf(1.f, maxn / mn);
        if (t < DDIM) mu_s[t] = m * f;
        float v = (t < DDIM) ? (m * f) * (m * f) : 0.f;
        mu2 = block_sum(v);
    }

    // ---- Karcher iterations: 1 barrier each ----
    for (int it = 0; it < FRECHET_ITERS_N; ++it) {
        float* buf = (it & 1) ? PA : PB;
        {
            float4 mu4 = ((const float4*)mu_s)[lane];
            dot_rows(mu4, d_s, false);
        }
        // per-point scalar chain: one THREAD per point (128 parallel chains)
        if (t < PPB) {
            float y2 = y2_s[t], d = d_s[t];
            float P = 1.f - 2.f * c * d;
            float den = fmaxf(P + c * c * mu2 * y2, EPSF);
            float A = -(P + c * y2) / den;
            float B = (1.f - c * mu2) / den;
            float mn2 = fmaxf(A * A * mu2 + 2.f * A * B * d + B * B * y2, EPSF);
            float mn = sqrtf(mn2);
            float tt = atanhf(fminf(sc * mn, TCLIP));
            float s = (fmaxf(1.f - c * mu2, EPSF) / sc) * tt / mn;
            w_s[t] = s * B;
            sA_s[t] = s * A;
        }
        __syncthreads();
        // weighted column sum X^T w (transposed, coalesced, no reduction)
        {
            const int dim = t & 255, seg = t >> 8;
            float acc = 0.f;
            for (int ii = 0; ii < 32; ++ii) {
                int i = seg * 32 + ii;
                acc += w_s[i] * x[(p0 + i) * DDIM + dim];
            }
            pseg[seg * DDIM + dim] = acc;
        }
        float sAv = (t < PPB) ? sA_s[t] : 0.f;
        float sAtot = block_sum(sAv);    // internal syncs also fence pseg
        if (t < DDIM)
            buf[b * PSTR + t] = pseg[t] + pseg[DDIM + t] + pseg[2 * DDIM + t] + pseg[3 * DDIM + t];
        if (t == 0) buf[b * PSTR + DDIM] = sAtot;
        gbar(bar, ++barno * NBLK);

        // finalize: mu <- expmap(mu, g), redundant per block
        float sv = 0.f;
        if (t < DDIM) for (int bb = 0; bb < NBLK; ++bb) sv += buf[bb * PSTR + t];
        float sa = (t < NBLK) ? buf[t * PSTR + DDIM] : 0.f;
        float sAt = block_sum(sa);
        float mu = (t < DDIM) ? mu_s[t] : 0.f;
        float g = sv * (1.f / NPTS) + (sAt * (1.f / NPTS)) * mu;
        float gn2 = block_sum(g * g);
        float mg  = block_sum(mu * g);
        float un = sqrtf(fmaxf(gn2, EPSF));
        float lam = 2.f / fmaxf(1.f - c * mu2, EPSF);
        float k = tanhf(sc * lam * un * 0.5f) / (sc * un);
        float sec = k * g;
        float ms = k * mg;
        float s2 = k * k * gn2;
        float aa = 1.f + 2.f * c * ms + c * s2;
        float bb2 = 1.f - c * mu2;
        float den = fmaxf(1.f + 2.f * c * ms + c * c * mu2 * s2, EPSF);
        float nmu = (aa * mu + bb2 * sec) / den;
        if (t < DDIM) mu_s[t] = nmu;
        float v2 = (t < DDIM) ? nmu * nmu : 0.f;
        mu2 = block_sum(v2);
    }

    // ---- variance pass ----
    float* vbuf = ((FRECHET_ITERS_N - 1) & 1) ? PB : PA;  // buffer NOT written by last iter
    {
        float4 mu4 = ((const float4*)mu_s)[lane];
        dot_rows(mu4, d_s, false);   // d_s kept for the output chain
    }
    if (t < PPB) {
        float y2 = y2_s[t], d = d_s[t];
        float P = 1.f - 2.f * c * d;
        float den = fmaxf(P + c * c * mu2 * y2, EPSF);
        float A = -(P + c * y2) / den;
        float B = (1.f - c * mu2) / den;
        float mn2 = fmaxf(A * A * mu2 + 2.f * A * B * d + B * B * y2, EPSF);
        float mn = sqrtf(mn2);
        float tt = atanhf(fminf(sc * mn, TCLIP));
        float dd = (2.f / sc) * tt;
        sA_s[t] = dd * dd;
    }
    __syncthreads();
    {
        float v = (t < PPB) ? sA_s[t] : 0.f;
        float tot = block_sum(v);
        if (t == 0) vbuf[b * PSTR + DDIM] = tot;
    }
    gbar(bar, ++barno * NBLK);

    float var, gamma;
    {
        float sa = (t < NBLK) ? vbuf[t * PSTR + DDIM] : 0.f;
        var = block_sum(sa) * (1.f / NPTS);
        gamma = sqrtf(var_param[0] / (var + 1e-6f));
    }

    // ---- transport/output scalars (uniform) ----
    float omu;
    {
        float muv = (t < DDIM) ? mu_s[t] : 0.f;
        float omv = (t < DDIM) ? om_s[t] : 0.f;
        omu = block_sum(omv * muv);
    }
    const float Amu = fmaxf(1.f - c * mu2, EPSF);
    const float Aom = fmaxf(1.f - c * om2, EPSF);
    const float ratio = Aom / Amu;           // lam_mu / lam_om
    const float aq = 1.f - 2.f * c * omu + c * mu2;
    const float bq = 1.f - c * om2;
    const float dqv = fmaxf(1.f - 2.f * c * omu + c * c * om2 * mu2, EPSF);
    const float qo = aq / dqv, qm = -bq / dqv;
    const float q2 = qo * qo * om2 + 2.f * qo * qm * omu + qm * qm * mu2;
    const float lam_om = 2.f / Aom;

    // ---- output chain: one thread per point ----
    if (t < PPB) {
        float y2 = y2_s[t], d = d_s[t], e = e_s[t];
        auto dotOm3 = [&](float po, float pm, float px) { return po * om2 + pm * omu + px * e; };
        auto dotMu3 = [&](float po, float pm, float px) { return po * omu + pm * mu2 + px * d; };
        auto sqn3 = [&](float po, float pm, float px) {
            return po * po * om2 + pm * pm * mu2 + px * px * y2
                 + 2.f * (po * pm * omu + po * px * e + pm * px * d);
        };

        // u = logmap(mu, x) = Um*mu + Ux*x
        float P = 1.f - 2.f * c * d;
        float den0 = fmaxf(P + c * c * mu2 * y2, EPSF);
        float A = -(P + c * y2) / den0;
        float B = (1.f - c * mu2) / den0;
        float mn2 = fmaxf(A * A * mu2 + 2.f * A * B * d + B * B * y2, EPSF);
        float mn = sqrtf(mn2);
        float tt = atanhf(fminf(sc * mn, TCLIP));
        float s = (fmaxf(1.f - c * mu2, EPSF) / sc) * tt / mn;
        float Um = s * A, Ux = s * B;

        // h1 = mobius_add(-mu, u)
        float xy1 = -dotMu3(0.f, Um, Ux);
        float Y21 = sqn3(0.f, Um, Ux);
        float a1 = 1.f + 2.f * c * xy1 + c * Y21;
        float b1 = 1.f - c * mu2;
        float dn1 = fmaxf(1.f + 2.f * c * xy1 + c * c * mu2 * Y21, EPSF);
        float h1m = (-a1 + b1 * Um) / dn1;
        float h1x = (b1 * Ux) / dn1;

        // h2 = mobius_add(om, h1)
        float xy2 = dotOm3(0.f, h1m, h1x);
        float Y22 = sqn3(0.f, h1m, h1x);
        float a2 = 1.f + 2.f * c * xy2 + c * Y22;
        float b2 = 1.f - c * om2;
        float dn2 = fmaxf(1.f + 2.f * c * xy2 + c * c * om2 * Y22, EPSF);
        float h2o = a2 / dn2;
        float h2m = (b2 * h1m) / dn2;
        float h2x = (b2 * h1x) / dn2;

        // g2 = mobius_add(-q, h2), q = qo*om + qm*mu
        float xy3 = -(qo * dotOm3(h2o, h2m, h2x) + qm * dotMu3(h2o, h2m, h2x));
        float Y23 = sqn3(h2o, h2m, h2x);
        float a3 = 1.f + 2.f * c * xy3 + c * Y23;
        float b3 = 1.f - c * q2;
        float dn3 = fmaxf(1.f + 2.f * c * xy3 + c * c * q2 * Y23, EPSF);
        float g2o = (-a3 * qo + b3 * h2o) / dn3;
        float g2m = (-a3 * qm + b3 * h2m) / dn3;
        float g2x = (b3 * h2x) / dn3;

        // L = ratio*gamma*g2 ; out = expmap(om, L)
        float k1 = ratio * gamma;
        float Lo = k1 * g2o, Lm = k1 * g2m, Lx = k1 * g2x;
        float un2 = sqn3(Lo, Lm, Lx);
        float un = sqrtf(fmaxf(un2, EPSF));
        float coef = tanhf(sc * lam_om * un * 0.5f) / (sc * un);
        float So = coef * Lo, Sm = coef * Lm, Sx = coef * Lx;
        float xy4 = dotOm3(So, Sm, Sx);
        float Y24 = coef * coef * un2;
        float a4 = 1.f + 2.f * c * xy4 + c * Y24;
        float b4 = 1.f - c * om2;
        float dn4 = fmaxf(1.f + 2.f * c * xy4 + c * c * om2 * Y24, EPSF);
        w_s[t]  = (a4 + b4 * So) / dn4;   // fo
        sA_s[t] = (b4 * Sm) / dn4;        // fm
        fx_s[t] = (b4 * Sx) / dn4;        // fx
    }
    __syncthreads();

    // ---- output store: wave per point, float4 coalesced ----
    {
        float4 mu4f = ((const float4*)mu_s)[lane];
        float4 om4f = ((const float4*)om_s)[lane];
        #pragma unroll
        for (int i = 0; i < PPW; ++i) {
            int pl = wv * PPW + i;
            float fo = w_s[pl], fm = sA_s[pl], fx = fx_s[pl];
            float4 x4 = xr[pl * 64 + lane];
            float4 o4;
            o4.x = fo * om4f.x + fm * mu4f.x + fx * x4.x;
            o4.y = fo * om4f.y + fm * mu4f.y + fx * x4.y;
            o4.z = fo * om4f.z + fm * mu4f.z + fx * x4.z;
            o4.w = fo * om4f.w + fm * mu4f.w + fx * x4.w;
            ((float4*)out)[(p0 + pl) * 64 + lane] = o4;
        }
    }
}

extern "C" void kernel_launch(void* const* d_in, const int* in_sizes, int n_in,
                              void* d_out, int out_size, void* d_ws, size_t ws_size,
                              hipStream_t stream) {
    const float* x = (const float*)d_in[0];
    const float* K = (const float*)d_in[1];
    const float* mean_param = (const float*)d_in[2];
    const float* var_param = (const float*)d_in[3];
    float* out = (float*)d_out;
    float* ws = (float*)d_ws;

    init_bar<<<1, 1, 0, stream>>>(ws);
    void* args[] = {(void*)&x, (void*)&K, (void*)&mean_param, (void*)&var_param,
                    (void*)&out, (void*)&ws};
    hipLaunchCooperativeKernel((const void*)rbn_fused, dim3(NBLK), dim3(NTHR),
                               args, 0, stream);
}

// Round 4
// 248.492 us; speedup vs baseline: 2.4688x; 2.2768x over previous
//
#include <hip/hip_runtime.h>
#include <math.h>

#define EPSF 1e-6f
#define TCLIP (1.0f - 1e-5f)
#define NPTS 16384
#define DDIM 256
#define NBLK 128
#define NTHR 1024
#define PPB 128   // points per block
#define NWAVE 16
#define PPW 8     // points per wave (held in registers: 8 x float4 = 32 VGPRs)
#define PSTR 260  // partial stride: 256 vec + 1 scalar + pad
#define FRECHET_ITERS_N 10

// ws float layout:
// [0]                    grid-barrier counter (unsigned, monotonic)
// [64, 64+NBLK*PSTR)     partial buffer A
// [.., +NBLK*PSTR)       partial buffer B
#define WS_BAR 0
#define WS_PA 64
#define WS_PB (WS_PA + NBLK * PSTR)

__device__ __forceinline__ float block_sum(float v) {
    __shared__ float s_bs[NWAVE];
    #pragma unroll
    for (int off = 32; off; off >>= 1) v += __shfl_xor(v, off);
    const int w = threadIdx.x >> 6, l = threadIdx.x & 63;
    __syncthreads();                 // protect s_bs reuse across calls
    if (l == 0) s_bs[w] = v;
    __syncthreads();
    float s = 0.f;
    #pragma unroll
    for (int i = 0; i < NWAVE; ++i) s += s_bs[i];
    return s;
}

// Fence-minimal monotonic grid barrier. Relaxed atomics (same sc1 bypass-L2
// visibility path as acquire/release, but NO per-op buffer_inv/buffer_wbl2);
// exactly one release fence on arrival and one acquire fence on exit.
__device__ __forceinline__ void gbar(unsigned* cnt, unsigned target) {
    __syncthreads();
    if (threadIdx.x == 0) {
        __builtin_amdgcn_fence(__ATOMIC_RELEASE, "agent");   // wb dirty partials
        __hip_atomic_fetch_add(cnt, 1u, __ATOMIC_RELAXED, __HIP_MEMORY_SCOPE_AGENT);
        while (__hip_atomic_load(cnt, __ATOMIC_RELAXED, __HIP_MEMORY_SCOPE_AGENT) < target)
            __builtin_amdgcn_s_sleep(4);
        __builtin_amdgcn_fence(__ATOMIC_ACQUIRE, "agent");   // inv L2 once
    }
    __syncthreads();
}

__global__ void init_bar(float* ws) { ((unsigned*)(ws + WS_BAR))[0] = 0u; }

__global__ __launch_bounds__(NTHR, 1) void rbn_fused(
    const float* __restrict__ x, const float* __restrict__ Kp,
    const float* __restrict__ mean_param, const float* __restrict__ var_param,
    float* __restrict__ out, float* __restrict__ ws)
{
    const float c = -Kp[0];
    const float sc = sqrtf(c);
    const int t = threadIdx.x, lane = t & 63, wv = t >> 6;
    const int b = blockIdx.x;
    const int p0 = b * PPB;
    const float4* xr = ((const float4*)x) + p0 * 64;

    unsigned* bar = (unsigned*)(ws + WS_BAR);
    float* PA = ws + WS_PA;
    float* PB = ws + WS_PB;

    __shared__ float mu_s[DDIM], om_s[DDIM];
    __shared__ float dpart[PPB * 65];   // padded: stride 65 breaks bank aliasing
    __shared__ float dqr[PPB * 9];      // padded: stride 9
    __shared__ float y2_s[PPB], e_s[PPB], d_s[PPB], w_s[PPB], sA_s[PPB], fx_s[PPB];
    __shared__ float pseg[NWAVE * DDIM];   // 16 wave-partials for column sums

    unsigned barno = 0;

    // ---- load this block's 128-point chunk into registers, once ----
    float4 xreg[PPW];
    #pragma unroll
    for (int i = 0; i < PPW; ++i)
        xreg[i] = xr[(wv * PPW + i) * 64 + lane];

    // batched per-point dot against a broadcast vector (register-resident x)
    auto dot_rows = [&](float4 v4, float* dst, bool self) {
        __syncthreads();
        #pragma unroll
        for (int i = 0; i < PPW; ++i) {
            float4 xv = xreg[i];
            float4 u4 = self ? xv : v4;
            dpart[(wv * PPW + i) * 65 + lane] =
                xv.x * u4.x + xv.y * u4.y + xv.z * u4.z + xv.w * u4.w;
        }
        __syncthreads();
        {
            int pl = t & 127, q = t >> 7;   // 8 threads per point
            float s = 0.f;
            #pragma unroll
            for (int j = 0; j < 8; ++j) s += dpart[pl * 65 + q * 8 + j];
            dqr[pl * 9 + q] = s;
        }
        __syncthreads();
        if (t < PPB) {
            float s = 0.f;
            #pragma unroll
            for (int j = 0; j < 8; ++j) s += dqr[t * 9 + j];
            dst[t] = s;
        }
        __syncthreads();
    };

    // weighted column sum over register-resident x: dst[t<256] = sum_i w_i x_i[t]
    // wgt == nullptr -> plain sum
    auto wsum_rows = [&](const float* wgt, float* dstv) {
        float4 a = make_float4(0.f, 0.f, 0.f, 0.f);
        #pragma unroll
        for (int i = 0; i < PPW; ++i) {
            float w = wgt ? wgt[wv * PPW + i] : 1.f;
            a.x += w * xreg[i].x; a.y += w * xreg[i].y;
            a.z += w * xreg[i].z; a.w += w * xreg[i].w;
        }
        __syncthreads();
        ((float4*)(pseg + wv * DDIM))[lane] = a;
        __syncthreads();
        if (t < DDIM) {
            float s = 0.f;
            #pragma unroll
            for (int w = 0; w < NWAVE; ++w) s += pseg[w * DDIM + t];
            dstv[t] = s;
        }
    };

    // ---- om = exp0(mean_param), redundant per block ----
    {
        float u = (t < DDIM) ? mean_param[t] : 0.f;
        float un2 = block_sum(u * u);
        float un = sqrtf(fmaxf(un2, EPSF));
        if (t < DDIM) om_s[t] = tanhf(sc * un) * u / (sc * un);
    }
    float om2;
    { float v = (t < DDIM) ? om_s[t] * om_s[t] : 0.f; om2 = block_sum(v); }

    // ---- precompute y2 and e = <om, x> ----
    dot_rows(make_float4(0.f, 0.f, 0.f, 0.f), y2_s, true);
    {
        float4 om4 = ((const float4*)om_s)[lane];
        dot_rows(om4, e_s, false);
    }

    // ---- Euclidean mean partial ----
    wsum_rows(nullptr, PA + b * PSTR);
    gbar(bar, ++barno * NBLK);

    // ---- init mu (redundant per block) ----
    float mu2;
    {
        float s = 0.f;
        if (t < DDIM) for (int bb = 0; bb < NBLK; ++bb) s += PA[bb * PSTR + t];
        float m = s * (1.f / NPTS);
        float mn2 = block_sum(m * m);
        float mn = sqrtf(fmaxf(mn2, EPSF));
        float maxn = (1.f - 1e-3f) / sc;
        float f = fminf(1.f, maxn / mn);
        if (t < DDIM) mu_s[t] = m * f;
        float v = (t < DDIM) ? (m * f) * (m * f) : 0.f;
        mu2 = block_sum(v);
    }

    // ---- Karcher iterations: 1 barrier each ----
    for (int it = 0; it < FRECHET_ITERS_N; ++it) {
        float* buf = (it & 1) ? PA : PB;
        {
            float4 mu4 = ((const float4*)mu_s)[lane];
            dot_rows(mu4, d_s, false);
        }
        // per-point scalar chain: one THREAD per point (128 parallel chains)
        if (t < PPB) {
            float y2 = y2_s[t], d = d_s[t];
            float P = 1.f - 2.f * c * d;
            float den = fmaxf(P + c * c * mu2 * y2, EPSF);
            float A = -(P + c * y2) / den;
            float B = (1.f - c * mu2) / den;
            float mn2 = fmaxf(A * A * mu2 + 2.f * A * B * d + B * B * y2, EPSF);
            float mn = sqrtf(mn2);
            float tt = atanhf(fminf(sc * mn, TCLIP));
            float s = (fmaxf(1.f - c * mu2, EPSF) / sc) * tt / mn;
            w_s[t] = s * B;
            sA_s[t] = s * A;
        }
        __syncthreads();
        wsum_rows(w_s, buf + b * PSTR);
        float sAv = (t < PPB) ? sA_s[t] : 0.f;
        float sAtot = block_sum(sAv);
        if (t == 0) buf[b * PSTR + DDIM] = sAtot;
        gbar(bar, ++barno * NBLK);

        // finalize: mu <- expmap(mu, g), redundant per block
        float sv = 0.f;
        if (t < DDIM) for (int bb = 0; bb < NBLK; ++bb) sv += buf[bb * PSTR + t];
        float sa = (t < NBLK) ? buf[t * PSTR + DDIM] : 0.f;
        float sAt = block_sum(sa);
        float mu = (t < DDIM) ? mu_s[t] : 0.f;
        float g = sv * (1.f / NPTS) + (sAt * (1.f / NPTS)) * mu;
        float gn2 = block_sum(g * g);
        float mg  = block_sum(mu * g);
        float un = sqrtf(fmaxf(gn2, EPSF));
        float lam = 2.f / fmaxf(1.f - c * mu2, EPSF);
        float k = tanhf(sc * lam * un * 0.5f) / (sc * un);
        float sec = k * g;
        float ms = k * mg;
        float s2 = k * k * gn2;
        float aa = 1.f + 2.f * c * ms + c * s2;
        float bb2 = 1.f - c * mu2;
        float den = fmaxf(1.f + 2.f * c * ms + c * c * mu2 * s2, EPSF);
        float nmu = (aa * mu + bb2 * sec) / den;
        if (t < DDIM) mu_s[t] = nmu;
        float v2 = (t < DDIM) ? nmu * nmu : 0.f;
        mu2 = block_sum(v2);
    }

    // ---- variance pass (uses buffer NOT written by the last iteration) ----
    float* vbuf = ((FRECHET_ITERS_N - 1) & 1) ? PB : PA;
    {
        float4 mu4 = ((const float4*)mu_s)[lane];
        dot_rows(mu4, d_s, false);   // d_s kept for the output chain
    }
    if (t < PPB) {
        float y2 = y2_s[t], d = d_s[t];
        float P = 1.f - 2.f * c * d;
        float den = fmaxf(P + c * c * mu2 * y2, EPSF);
        float A = -(P + c * y2) / den;
        float B = (1.f - c * mu2) / den;
        float mn2 = fmaxf(A * A * mu2 + 2.f * A * B * d + B * B * y2, EPSF);
        float mn = sqrtf(mn2);
        float tt = atanhf(fminf(sc * mn, TCLIP));
        float dd = (2.f / sc) * tt;
        sA_s[t] = dd * dd;
    }
    __syncthreads();
    {
        float v = (t < PPB) ? sA_s[t] : 0.f;
        float tot = block_sum(v);
        if (t == 0) vbuf[b * PSTR + DDIM] = tot;
    }
    gbar(bar, ++barno * NBLK);

    float var, gamma;
    {
        float sa = (t < NBLK) ? vbuf[t * PSTR + DDIM] : 0.f;
        var = block_sum(sa) * (1.f / NPTS);
        gamma = sqrtf(var_param[0] / (var + 1e-6f));
    }

    // ---- transport/output scalars (uniform) ----
    float omu;
    {
        float muv = (t < DDIM) ? mu_s[t] : 0.f;
        float omv = (t < DDIM) ? om_s[t] : 0.f;
        omu = block_sum(omv * muv);
    }
    const float Amu = fmaxf(1.f - c * mu2, EPSF);
    const float Aom = fmaxf(1.f - c * om2, EPSF);
    const float ratio = Aom / Amu;           // lam_mu / lam_om
    const float aq = 1.f - 2.f * c * omu + c * mu2;
    const float bq = 1.f - c * om2;
    const float dqv = fmaxf(1.f - 2.f * c * omu + c * c * om2 * mu2, EPSF);
    const float qo = aq / dqv, qm = -bq / dqv;
    const float q2 = qo * qo * om2 + 2.f * qo * qm * omu + qm * qm * mu2;
    const float lam_om = 2.f / Aom;

    // ---- output chain: one thread per point ----
    if (t < PPB) {
        float y2 = y2_s[t], d = d_s[t], e = e_s[t];
        auto dotOm3 = [&](float po, float pm, float px) { return po * om2 + pm * omu + px * e; };
        auto dotMu3 = [&](float po, float pm, float px) { return po * omu + pm * mu2 + px * d; };
        auto sqn3 = [&](float po, float pm, float px) {
            return po * po * om2 + pm * pm * mu2 + px * px * y2
                 + 2.f * (po * pm * omu + po * px * e + pm * px * d);
        };

        // u = logmap(mu, x) = Um*mu + Ux*x
        float P = 1.f - 2.f * c * d;
        float den0 = fmaxf(P + c * c * mu2 * y2, EPSF);
        float A = -(P + c * y2) / den0;
        float B = (1.f - c * mu2) / den0;
        float mn2 = fmaxf(A * A * mu2 + 2.f * A * B * d + B * B * y2, EPSF);
        float mn = sqrtf(mn2);
        float tt = atanhf(fminf(sc * mn, TCLIP));
        float s = (fmaxf(1.f - c * mu2, EPSF) / sc) * tt / mn;
        float Um = s * A, Ux = s * B;

        // h1 = mobius_add(-mu, u)
        float xy1 = -dotMu3(0.f, Um, Ux);
        float Y21 = sqn3(0.f, Um, Ux);
        float a1 = 1.f + 2.f * c * xy1 + c * Y21;
        float b1 = 1.f - c * mu2;
        float dn1 = fmaxf(1.f + 2.f * c * xy1 + c * c * mu2 * Y21, EPSF);
        float h1m = (-a1 + b1 * Um) / dn1;
        float h1x = (b1 * Ux) / dn1;

        // h2 = mobius_add(om, h1)
        float xy2 = dotOm3(0.f, h1m, h1x);
        float Y22 = sqn3(0.f, h1m, h1x);
        float a2 = 1.f + 2.f * c * xy2 + c * Y22;
        float b2 = 1.f - c * om2;
        float dn2 = fmaxf(1.f + 2.f * c * xy2 + c * c * om2 * Y22, EPSF);
        float h2o = a2 / dn2;
        float h2m = (b2 * h1m) / dn2;
        float h2x = (b2 * h1x) / dn2;

        // g2 = mobius_add(-q, h2), q = qo*om + qm*mu
        float xy3 = -(qo * dotOm3(h2o, h2m, h2x) + qm * dotMu3(h2o, h2m, h2x));
        float Y23 = sqn3(h2o, h2m, h2x);
        float a3 = 1.f + 2.f * c * xy3 + c * Y23;
        float b3 = 1.f - c * q2;
        float dn3 = fmaxf(1.f + 2.f * c * xy3 + c * c * q2 * Y23, EPSF);
        float g2o = (-a3 * qo + b3 * h2o) / dn3;
        float g2m = (-a3 * qm + b3 * h2m) / dn3;
        float g2x = (b3 * h2x) / dn3;

        // L = ratio*gamma*g2 ; out = expmap(om, L)
        float k1 = ratio * gamma;
        float Lo = k1 * g2o, Lm = k1 * g2m, Lx = k1 * g2x;
        float un2 = sqn3(Lo, Lm, Lx);
        float un = sqrtf(fmaxf(un2, EPSF));
        float coef = tanhf(sc * lam_om * un * 0.5f) / (sc * un);
        float So = coef * Lo, Sm = coef * Lm, Sx = coef * Lx;
        float xy4 = dotOm3(So, Sm, Sx);
        float Y24 = coef * coef * un2;
        float a4 = 1.f + 2.f * c * xy4 + c * Y24;
        float b4 = 1.f - c * om2;
        float dn4 = fmaxf(1.f + 2.f * c * xy4 + c * c * om2 * Y24, EPSF);
        w_s[t]  = (a4 + b4 * So) / dn4;   // fo
        sA_s[t] = (b4 * Sm) / dn4;        // fm
        fx_s[t] = (b4 * Sx) / dn4;        // fx
    }
    __syncthreads();

    // ---- output store from registers, float4 coalesced ----
    {
        float4 mu4f = ((const float4*)mu_s)[lane];
        float4 om4f = ((const float4*)om_s)[lane];
        #pragma unroll
        for (int i = 0; i < PPW; ++i) {
            int pl = wv * PPW + i;
            float fo = w_s[pl], fm = sA_s[pl], fx = fx_s[pl];
            float4 x4 = xreg[i];
            float4 o4;
            o4.x = fo * om4f.x + fm * mu4f.x + fx * x4.x;
            o4.y = fo * om4f.y + fm * mu4f.y + fx * x4.y;
            o4.z = fo * om4f.z + fm * mu4f.z + fx * x4.z;
            o4.w = fo * om4f.w + fm * mu4f.w + fx * x4.w;
            ((float4*)out)[(p0 + pl) * 64 + lane] = o4;
        }
    }
}

extern "C" void kernel_launch(void* const* d_in, const int* in_sizes, int n_in,
                              void* d_out, int out_size, void* d_ws, size_t ws_size,
                              hipStream_t stream) {
    const float* x = (const float*)d_in[0];
    const float* K = (const float*)d_in[1];
    const float* mean_param = (const float*)d_in[2];
    const float* var_param = (const float*)d_in[3];
    float* out = (float*)d_out;
    float* ws = (float*)d_ws;

    init_bar<<<1, 1, 0, stream>>>(ws);
    void* args[] = {(void*)&x, (void*)&K, (void*)&mean_param, (void*)&var_param,
                    (void*)&out, (void*)&ws};
    hipLaunchCooperativeKernel((const void*)rbn_fused, dim3(NBLK), dim3(NTHR),
                               args, 0, stream);
}

// Round 5
// 239.328 us; speedup vs baseline: 2.5633x; 1.0383x over previous
//
#include <hip/hip_runtime.h>
#include <math.h>

#define EPSF 1e-6f
#define TCLIP (1.0f - 1e-5f)
#define NPTS 16384
#define DDIM 256
#define NBLK 128
#define NTHR 1024
#define PPB 128   // points per block
#define NWAVE 16
#define PPW 8     // points per wave (held in registers: 8 x float4 = 32 VGPRs)
#define PSTR 260  // partial stride: 256 vec + 1 scalar + pad (1040 B, 16B-aligned)
#define FRECHET_ITERS_N 10

// ws float layout:
// [0]                    grid-barrier counter (unsigned, monotonic)
// [64, 64+NBLK*PSTR)     partial buffer A
// [.., +NBLK*PSTR)       partial buffer B
#define WS_BAR 0
#define WS_PA 64
#define WS_PB (WS_PA + NBLK * PSTR)

__device__ __forceinline__ float block_sum(float v) {
    __shared__ float s_bs[NWAVE];
    #pragma unroll
    for (int off = 32; off; off >>= 1) v += __shfl_xor(v, off);
    const int w = threadIdx.x >> 6, l = threadIdx.x & 63;
    __syncthreads();                 // protect s_bs reuse across calls
    if (l == 0) s_bs[w] = v;
    __syncthreads();
    float s = 0.f;
    #pragma unroll
    for (int i = 0; i < NWAVE; ++i) s += s_bs[i];
    return s;
}

// Fence-minimal monotonic grid barrier (one release + one acquire per block).
__device__ __forceinline__ void gbar(unsigned* cnt, unsigned target) {
    __syncthreads();
    if (threadIdx.x == 0) {
        __builtin_amdgcn_fence(__ATOMIC_RELEASE, "agent");   // wb dirty partials
        __hip_atomic_fetch_add(cnt, 1u, __ATOMIC_RELAXED, __HIP_MEMORY_SCOPE_AGENT);
        while (__hip_atomic_load(cnt, __ATOMIC_RELAXED, __HIP_MEMORY_SCOPE_AGENT) < target)
            __builtin_amdgcn_s_sleep(2);
        __builtin_amdgcn_fence(__ATOMIC_ACQUIRE, "agent");   // inv once
    }
    __syncthreads();
}

__global__ void init_bar(float* ws) { ((unsigned*)(ws + WS_BAR))[0] = 0u; }

__global__ __launch_bounds__(NTHR, 1) void rbn_fused(
    const float* __restrict__ x, const float* __restrict__ Kp,
    const float* __restrict__ mean_param, const float* __restrict__ var_param,
    float* __restrict__ out, float* __restrict__ ws)
{
    const float c = -Kp[0];
    const float sc = sqrtf(c);
    const int t = threadIdx.x, lane = t & 63, wv = t >> 6;
    const int b = blockIdx.x;
    const int p0 = b * PPB;
    const float4* xr = ((const float4*)x) + p0 * 64;

    unsigned* bar = (unsigned*)(ws + WS_BAR);
    float* PA = ws + WS_PA;
    float* PB = ws + WS_PB;

    __shared__ float mu_s[DDIM], om_s[DDIM], g_s[DDIM];
    __shared__ float dpart[PPB * 65];   // padded: stride 65 breaks bank aliasing
    __shared__ float dqr[PPB * 9];      // padded: stride 9
    __shared__ float y2_s[PPB], e_s[PPB], d_s[PPB], w_s[PPB], sA_s[PPB], fx_s[PPB];
    __shared__ float pseg[NWAVE * DDIM];   // 16 partial rows for column sums

    unsigned barno = 0;

    // ---- load this block's 128-point chunk into registers, once ----
    float4 xreg[PPW];
    #pragma unroll
    for (int i = 0; i < PPW; ++i)
        xreg[i] = xr[(wv * PPW + i) * 64 + lane];

    // batched per-point dot against a broadcast vector (register-resident x)
    auto dot_rows = [&](float4 v4, float* dst, bool self) {
        __syncthreads();
        #pragma unroll
        for (int i = 0; i < PPW; ++i) {
            float4 xv = xreg[i];
            float4 u4 = self ? xv : v4;
            dpart[(wv * PPW + i) * 65 + lane] =
                xv.x * u4.x + xv.y * u4.y + xv.z * u4.z + xv.w * u4.w;
        }
        __syncthreads();
        {
            int pl = t & 127, q = t >> 7;   // 8 threads per point
            float s = 0.f;
            #pragma unroll
            for (int j = 0; j < 8; ++j) s += dpart[pl * 65 + q * 8 + j];
            dqr[pl * 9 + q] = s;
        }
        __syncthreads();
        if (t < PPB) {
            float s = 0.f;
            #pragma unroll
            for (int j = 0; j < 8; ++j) s += dqr[t * 9 + j];
            dst[t] = s;
        }
        __syncthreads();
    };

    // weighted column sum over register-resident x: dstv[t<256] = sum_i w_i x_i[t]
    auto wsum_rows = [&](const float* wgt, float* dstv) {
        float4 a = make_float4(0.f, 0.f, 0.f, 0.f);
        #pragma unroll
        for (int i = 0; i < PPW; ++i) {
            float w = wgt ? wgt[wv * PPW + i] : 1.f;
            a.x += w * xreg[i].x; a.y += w * xreg[i].y;
            a.z += w * xreg[i].z; a.w += w * xreg[i].w;
        }
        __syncthreads();
        ((float4*)(pseg + wv * DDIM))[lane] = a;
        __syncthreads();
        if (t < DDIM) {
            float s = 0.f;
            #pragma unroll
            for (int w = 0; w < NWAVE; ++w) s += pseg[w * DDIM + t];
            dstv[t] = s;
        }
    };

    // cross-block vector reduce: dstv[t<256] = sum over 128 partial rows.
    // All 1024 threads: thread = (dim-group of 4, segment of 8 rows),
    // 8 independent float4 loads each -> 16-way LDS combine.
    auto reduce128 = [&](const float* buf, float* dstv) {
        const int dg = t & 63, sg = t >> 6;
        float4 a = make_float4(0.f, 0.f, 0.f, 0.f);
        #pragma unroll
        for (int j = 0; j < 8; ++j) {
            float4 v = ((const float4*)(buf + (sg * 8 + j) * PSTR))[dg];
            a.x += v.x; a.y += v.y; a.z += v.z; a.w += v.w;
        }
        __syncthreads();                 // pseg reuse guard
        ((float4*)(pseg + sg * DDIM))[dg] = a;
        __syncthreads();
        if (t < DDIM) {
            float s = 0.f;
            #pragma unroll
            for (int w = 0; w < NWAVE; ++w) s += pseg[w * DDIM + t];
            dstv[t] = s;
        }
        __syncthreads();
    };

    // ---- om = exp0(mean_param), redundant per block ----
    {
        float u = (t < DDIM) ? mean_param[t] : 0.f;
        float un2 = block_sum(u * u);
        float un = sqrtf(fmaxf(un2, EPSF));
        if (t < DDIM) om_s[t] = tanhf(sc * un) * u / (sc * un);
    }
    float om2;
    { float v = (t < DDIM) ? om_s[t] * om_s[t] : 0.f; om2 = block_sum(v); }

    // ---- precompute y2 and e = <om, x> ----
    dot_rows(make_float4(0.f, 0.f, 0.f, 0.f), y2_s, true);
    {
        float4 om4 = ((const float4*)om_s)[lane];
        dot_rows(om4, e_s, false);
    }

    // ---- Euclidean mean partial ----
    wsum_rows(nullptr, PA + b * PSTR);
    gbar(bar, ++barno * NBLK);

    // ---- init mu (redundant per block, vectorized reduce) ----
    float mu2;
    {
        reduce128(PA, g_s);
        float m = (t < DDIM) ? g_s[t] * (1.f / NPTS) : 0.f;
        float mn2 = block_sum(m * m);
        float mn = sqrtf(fmaxf(mn2, EPSF));
        float maxn = (1.f - 1e-3f) / sc;
        float f = fminf(1.f, maxn / mn);
        if (t < DDIM) mu_s[t] = m * f;
        float v = (m * f) * (m * f);
        mu2 = block_sum(v);
    }

    // ---- Karcher iterations: 1 barrier each ----
    for (int it = 0; it < FRECHET_ITERS_N; ++it) {
        float* buf = (it & 1) ? PA : PB;
        {
            float4 mu4 = ((const float4*)mu_s)[lane];
            dot_rows(mu4, d_s, false);
        }
        // per-point scalar chain: one THREAD per point (128 parallel chains)
        if (t < PPB) {
            float y2 = y2_s[t], d = d_s[t];
            float P = 1.f - 2.f * c * d;
            float den = fmaxf(P + c * c * mu2 * y2, EPSF);
            float A = -(P + c * y2) / den;
            float B = (1.f - c * mu2) / den;
            float mn2 = fmaxf(A * A * mu2 + 2.f * A * B * d + B * B * y2, EPSF);
            float mn = sqrtf(mn2);
            float tt = atanhf(fminf(sc * mn, TCLIP));
            float s = (fmaxf(1.f - c * mu2, EPSF) / sc) * tt / mn;
            w_s[t] = s * B;
            sA_s[t] = s * A;
        }
        __syncthreads();
        wsum_rows(w_s, buf + b * PSTR);
        float sAv = (t < PPB) ? sA_s[t] : 0.f;
        float sAtot = block_sum(sAv);
        if (t == 0) buf[b * PSTR + DDIM] = sAtot;
        gbar(bar, ++barno * NBLK);

        // finalize: mu <- expmap(mu, g), redundant per block
        reduce128(buf, g_s);
        float sa = (t < NBLK) ? buf[t * PSTR + DDIM] : 0.f;
        float sAt = block_sum(sa);
        float mu = (t < DDIM) ? mu_s[t] : 0.f;
        float g = (t < DDIM) ? g_s[t] * (1.f / NPTS) + (sAt * (1.f / NPTS)) * mu : 0.f;
        float gn2 = block_sum(g * g);
        float mg  = block_sum(mu * g);
        float un = sqrtf(fmaxf(gn2, EPSF));
        float lam = 2.f / fmaxf(1.f - c * mu2, EPSF);
        float k = tanhf(sc * lam * un * 0.5f) / (sc * un);
        float sec = k * g;
        float ms = k * mg;
        float s2 = k * k * gn2;
        float aa = 1.f + 2.f * c * ms + c * s2;
        float bb2 = 1.f - c * mu2;
        float den = fmaxf(1.f + 2.f * c * ms + c * c * mu2 * s2, EPSF);
        float nmu = (aa * mu + bb2 * sec) / den;
        if (t < DDIM) mu_s[t] = nmu;
        float v2 = (t < DDIM) ? nmu * nmu : 0.f;
        mu2 = block_sum(v2);
    }

    // ---- variance pass (uses buffer NOT written by the last iteration) ----
    float* vbuf = ((FRECHET_ITERS_N - 1) & 1) ? PB : PA;
    {
        float4 mu4 = ((const float4*)mu_s)[lane];
        dot_rows(mu4, d_s, false);   // d_s kept for the output chain
    }
    if (t < PPB) {
        float y2 = y2_s[t], d = d_s[t];
        float P = 1.f - 2.f * c * d;
        float den = fmaxf(P + c * c * mu2 * y2, EPSF);
        float A = -(P + c * y2) / den;
        float B = (1.f - c * mu2) / den;
        float mn2 = fmaxf(A * A * mu2 + 2.f * A * B * d + B * B * y2, EPSF);
        float mn = sqrtf(mn2);
        float tt = atanhf(fminf(sc * mn, TCLIP));
        float dd = (2.f / sc) * tt;
        sA_s[t] = dd * dd;
    }
    __syncthreads();
    {
        float v = (t < PPB) ? sA_s[t] : 0.f;
        float tot = block_sum(v);
        if (t == 0) vbuf[b * PSTR + DDIM] = tot;
    }
    gbar(bar, ++barno * NBLK);

    float var, gamma;
    {
        float sa = (t < NBLK) ? vbuf[t * PSTR + DDIM] : 0.f;
        var = block_sum(sa) * (1.f / NPTS);
        gamma = sqrtf(var_param[0] / (var + 1e-6f));
    }

    // ---- transport/output scalars (uniform) ----
    float omu;
    {
        float muv = (t < DDIM) ? mu_s[t] : 0.f;
        float omv = (t < DDIM) ? om_s[t] : 0.f;
        omu = block_sum(omv * muv);
    }
    const float Amu = fmaxf(1.f - c * mu2, EPSF);
    const float Aom = fmaxf(1.f - c * om2, EPSF);
    const float ratio = Aom / Amu;           // lam_mu / lam_om
    const float aq = 1.f - 2.f * c * omu + c * mu2;
    const float bq = 1.f - c * om2;
    const float dqv = fmaxf(1.f - 2.f * c * omu + c * c * om2 * mu2, EPSF);
    const float qo = aq / dqv, qm = -bq / dqv;
    const float q2 = qo * qo * om2 + 2.f * qo * qm * omu + qm * qm * mu2;
    const float lam_om = 2.f / Aom;

    // ---- output chain: one thread per point ----
    if (t < PPB) {
        float y2 = y2_s[t], d = d_s[t], e = e_s[t];
        auto dotOm3 = [&](float po, float pm, float px) { return po * om2 + pm * omu + px * e; };
        auto dotMu3 = [&](float po, float pm, float px) { return po * omu + pm * mu2 + px * d; };
        auto sqn3 = [&](float po, float pm, float px) {
            return po * po * om2 + pm * pm * mu2 + px * px * y2
                 + 2.f * (po * pm * omu + po * px * e + pm * px * d);
        };

        // u = logmap(mu, x) = Um*mu + Ux*x
        float P = 1.f - 2.f * c * d;
        float den0 = fmaxf(P + c * c * mu2 * y2, EPSF);
        float A = -(P + c * y2) / den0;
        float B = (1.f - c * mu2) / den0;
        float mn2 = fmaxf(A * A * mu2 + 2.f * A * B * d + B * B * y2, EPSF);
        float mn = sqrtf(mn2);
        float tt = atanhf(fminf(sc * mn, TCLIP));
        float s = (fmaxf(1.f - c * mu2, EPSF) / sc) * tt / mn;
        float Um = s * A, Ux = s * B;

        // h1 = mobius_add(-mu, u)
        float xy1 = -dotMu3(0.f, Um, Ux);
        float Y21 = sqn3(0.f, Um, Ux);
        float a1 = 1.f + 2.f * c * xy1 + c * Y21;
        float b1 = 1.f - c * mu2;
        float dn1 = fmaxf(1.f + 2.f * c * xy1 + c * c * mu2 * Y21, EPSF);
        float h1m = (-a1 + b1 * Um) / dn1;
        float h1x = (b1 * Ux) / dn1;

        // h2 = mobius_add(om, h1)
        float xy2 = dotOm3(0.f, h1m, h1x);
        float Y22 = sqn3(0.f, h1m, h1x);
        float a2 = 1.f + 2.f * c * xy2 + c * Y22;
        float b2 = 1.f - c * om2;
        float dn2 = fmaxf(1.f + 2.f * c * xy2 + c * c * om2 * Y22, EPSF);
        float h2o = a2 / dn2;
        float h2m = (b2 * h1m) / dn2;
        float h2x = (b2 * h1x) / dn2;

        // g2 = mobius_add(-q, h2), q = qo*om + qm*mu
        float xy3 = -(qo * dotOm3(h2o, h2m, h2x) + qm * dotMu3(h2o, h2m, h2x));
        float Y23 = sqn3(h2o, h2m, h2x);
        float a3 = 1.f + 2.f * c * xy3 + c * Y23;
        float b3 = 1.f - c * q2;
        float dn3 = fmaxf(1.f + 2.f * c * xy3 + c * c * q2 * Y23, EPSF);
        float g2o = (-a3 * qo + b3 * h2o) / dn3;
        float g2m = (-a3 * qm + b3 * h2m) / dn3;
        float g2x = (b3 * h2x) / dn3;

        // L = ratio*gamma*g2 ; out = expmap(om, L)
        float k1 = ratio * gamma;
        float Lo = k1 * g2o, Lm = k1 * g2m, Lx = k1 * g2x;
        float un2 = sqn3(Lo, Lm, Lx);
        float un = sqrtf(fmaxf(un2, EPSF));
        float coef = tanhf(sc * lam_om * un * 0.5f) / (sc * un);
        float So = coef * Lo, Sm = coef * Lm, Sx = coef * Lx;
        float xy4 = dotOm3(So, Sm, Sx);
        float Y24 = coef * coef * un2;
        float a4 = 1.f + 2.f * c * xy4 + c * Y24;
        float b4 = 1.f - c * om2;
        float dn4 = fmaxf(1.f + 2.f * c * xy4 + c * c * om2 * Y24, EPSF);
        w_s[t]  = (a4 + b4 * So) / dn4;   // fo
        sA_s[t] = (b4 * Sm) / dn4;        // fm
        fx_s[t] = (b4 * Sx) / dn4;        // fx
    }
    __syncthreads();

    // ---- output store from registers, float4 coalesced ----
    {
        float4 mu4f = ((const float4*)mu_s)[lane];
        float4 om4f = ((const float4*)om_s)[lane];
        #pragma unroll
        for (int i = 0; i < PPW; ++i) {
            int pl = wv * PPW + i;
            float fo = w_s[pl], fm = sA_s[pl], fx = fx_s[pl];
            float4 x4 = xreg[i];
            float4 o4;
            o4.x = fo * om4f.x + fm * mu4f.x + fx * x4.x;
            o4.y = fo * om4f.y + fm * mu4f.y + fx * x4.y;
            o4.z = fo * om4f.z + fm * mu4f.z + fx * x4.z;
            o4.w = fo * om4f.w + fm * mu4f.w + fx * x4.w;
            ((float4*)out)[(p0 + pl) * 64 + lane] = o4;
        }
    }
}

extern "C" void kernel_launch(void* const* d_in, const int* in_sizes, int n_in,
                              void* d_out, int out_size, void* d_ws, size_t ws_size,
                              hipStream_t stream) {
    const float* x = (const float*)d_in[0];
    const float* K = (const float*)d_in[1];
    const float* mean_param = (const float*)d_in[2];
    const float* var_param = (const float*)d_in[3];
    float* out = (float*)d_out;
    float* ws = (float*)d_ws;

    init_bar<<<1, 1, 0, stream>>>(ws);
    void* args[] = {(void*)&x, (void*)&K, (void*)&mean_param, (void*)&var_param,
                    (void*)&out, (void*)&ws};
    hipLaunchCooperativeKernel((const void*)rbn_fused, dim3(NBLK), dim3(NTHR),
                               args, 0, stream);
}

// Round 6
// 206.919 us; speedup vs baseline: 2.9648x; 1.1566x over previous
//
#include <hip/hip_runtime.h>
#include <math.h>
#include <string.h>

#define EPSF 1e-6f
#define TCLIP (1.0f - 1e-5f)
#define NPTS 16384
#define DDIM 256
#define NBLK 128
#define NTHR 1024
#define PPB 128   // points per block
#define NWAVE 16
#define PPW 8     // points per wave (held in registers: 8 x float4 = 32 VGPRs)
#define PSTR 260  // partial stride: 256 vec + 1 scalar + pad (even -> 8B aligned rows)
#define FRECHET_ITERS_N 10

// ws float layout:
// [0]                    grid-barrier counter (unsigned, monotonic)
// [64, 64+NBLK*PSTR)     partial buffer A   (ALL accesses via sc1 atomics)
// [.., +NBLK*PSTR)       partial buffer B
#define WS_BAR 0
#define WS_PA 64
#define WS_PB (WS_PA + NBLK * PSTR)

// --- coherent-path (sc1) accessors: bypass/write-through L2, no fences needed ---
__device__ __forceinline__ void st_pair_sc1(float* addr, float a, float b) {
    float2 f2 = make_float2(a, b);
    double dv; memcpy(&dv, &f2, 8);
    __hip_atomic_store((double*)addr, dv, __ATOMIC_RELAXED, __HIP_MEMORY_SCOPE_AGENT);
}
__device__ __forceinline__ float2 ld_pair_sc1(const float* addr) {
    double dv = __hip_atomic_load((const double*)addr, __ATOMIC_RELAXED, __HIP_MEMORY_SCOPE_AGENT);
    float2 f2; memcpy(&f2, &dv, 8);
    return f2;
}
__device__ __forceinline__ void st_f_sc1(float* addr, float v) {
    __hip_atomic_store(addr, v, __ATOMIC_RELAXED, __HIP_MEMORY_SCOPE_AGENT);
}
__device__ __forceinline__ float ld_f_sc1(const float* addr) {
    return __hip_atomic_load(addr, __ATOMIC_RELAXED, __HIP_MEMORY_SCOPE_AGENT);
}

__device__ __forceinline__ float block_sum(float v) {
    __shared__ float s_bs[NWAVE];
    #pragma unroll
    for (int off = 32; off; off >>= 1) v += __shfl_xor(v, off);
    const int w = threadIdx.x >> 6, l = threadIdx.x & 63;
    __syncthreads();                 // protect s_bs reuse across calls
    if (l == 0) s_bs[w] = v;
    __syncthreads();
    float s = 0.f;
    #pragma unroll
    for (int i = 0; i < NWAVE; ++i) s += s_bs[i];
    return s;
}

// Monotonic grid barrier with ZERO cache-maintenance ops. All shared data
// travels the sc1 coherent path, so no wbl2/inv is required; __syncthreads()
// drains each wave's vmcnt (workgroup release fence) before arrival.
__device__ __forceinline__ void gbar(unsigned* cnt, unsigned target) {
    __syncthreads();
    if (threadIdx.x == 0) {
        __hip_atomic_fetch_add(cnt, 1u, __ATOMIC_RELAXED, __HIP_MEMORY_SCOPE_AGENT);
        while (__hip_atomic_load(cnt, __ATOMIC_RELAXED, __HIP_MEMORY_SCOPE_AGENT) < target)
            __builtin_amdgcn_s_sleep(1);
    }
    __syncthreads();
}

__global__ void init_bar(float* ws) { ((unsigned*)(ws + WS_BAR))[0] = 0u; }

__global__ __launch_bounds__(NTHR, 1) void rbn_fused(
    const float* __restrict__ x, const float* __restrict__ Kp,
    const float* __restrict__ mean_param, const float* __restrict__ var_param,
    float* __restrict__ out, float* __restrict__ ws)
{
    const float c = -Kp[0];
    const float sc = sqrtf(c);
    const int t = threadIdx.x, lane = t & 63, wv = t >> 6;
    const int b = blockIdx.x;
    const int p0 = b * PPB;
    const float4* xr = ((const float4*)x) + p0 * 64;

    unsigned* bar = (unsigned*)(ws + WS_BAR);
    float* PA = ws + WS_PA;
    float* PB = ws + WS_PB;

    __shared__ float mu_s[DDIM], om_s[DDIM], g_s[DDIM];
    __shared__ float dpart[PPB * 65];   // padded: stride 65 breaks bank aliasing
    __shared__ float dqr[PPB * 9];      // padded: stride 9
    __shared__ float y2_s[PPB], e_s[PPB], d_s[PPB], w_s[PPB], sA_s[PPB], fx_s[PPB];
    __shared__ float pseg[NWAVE * DDIM];   // partial rows for column sums

    unsigned barno = 0;

    // ---- load this block's 128-point chunk into registers, once ----
    float4 xreg[PPW];
    #pragma unroll
    for (int i = 0; i < PPW; ++i)
        xreg[i] = xr[(wv * PPW + i) * 64 + lane];

    // batched per-point dot against a broadcast vector (register-resident x)
    auto dot_rows = [&](float4 v4, float* dst, bool self) {
        __syncthreads();
        #pragma unroll
        for (int i = 0; i < PPW; ++i) {
            float4 xv = xreg[i];
            float4 u4 = self ? xv : v4;
            dpart[(wv * PPW + i) * 65 + lane] =
                xv.x * u4.x + xv.y * u4.y + xv.z * u4.z + xv.w * u4.w;
        }
        __syncthreads();
        {
            int pl = t & 127, q = t >> 7;   // 8 threads per point
            float s = 0.f;
            #pragma unroll
            for (int j = 0; j < 8; ++j) s += dpart[pl * 65 + q * 8 + j];
            dqr[pl * 9 + q] = s;
        }
        __syncthreads();
        if (t < PPB) {
            float s = 0.f;
            #pragma unroll
            for (int j = 0; j < 8; ++j) s += dqr[t * 9 + j];
            dst[t] = s;
        }
        __syncthreads();
    };

    // weighted column sum over register-resident x -> sc1 store of partial row
    auto wsum_rows = [&](const float* wgt, float* dstv) {
        float4 a = make_float4(0.f, 0.f, 0.f, 0.f);
        #pragma unroll
        for (int i = 0; i < PPW; ++i) {
            float w = wgt ? wgt[wv * PPW + i] : 1.f;
            a.x += w * xreg[i].x; a.y += w * xreg[i].y;
            a.z += w * xreg[i].z; a.w += w * xreg[i].w;
        }
        __syncthreads();
        ((float4*)(pseg + wv * DDIM))[lane] = a;
        __syncthreads();
        float s = 0.f;
        if (t < DDIM) {
            #pragma unroll
            for (int w = 0; w < NWAVE; ++w) s += pseg[w * DDIM + t];
        }
        float partner = __shfl_xor(s, 1);      // wave-uniform exec
        if (t < DDIM && !(t & 1))
            st_pair_sc1(dstv + t, s, partner);
    };

    // cross-block vector reduce: dstv[t<256] = sum over 128 partial rows.
    // thread = (dim-pair dg, segment sg of 16 rows): 16 independent sc1 8B loads
    auto reduce128 = [&](const float* buf, float* dstv) {
        const int dg = t & 127, sg = t >> 7;
        float ax = 0.f, ay = 0.f;
        #pragma unroll
        for (int j = 0; j < 16; ++j) {
            float2 v = ld_pair_sc1(buf + (sg * 16 + j) * PSTR + 2 * dg);
            ax += v.x; ay += v.y;
        }
        __syncthreads();                 // pseg reuse guard
        ((float2*)(pseg + sg * DDIM))[dg] = make_float2(ax, ay);
        __syncthreads();
        if (t < DDIM) {
            float s = 0.f;
            #pragma unroll
            for (int w = 0; w < 8; ++w) s += pseg[w * DDIM + t];
            dstv[t] = s;
        }
        __syncthreads();
    };

    // ---- om = exp0(mean_param), redundant per block ----
    {
        float u = (t < DDIM) ? mean_param[t] : 0.f;
        float un2 = block_sum(u * u);
        float un = sqrtf(fmaxf(un2, EPSF));
        if (t < DDIM) om_s[t] = tanhf(sc * un) * u / (sc * un);
    }
    float om2;
    { float v = (t < DDIM) ? om_s[t] * om_s[t] : 0.f; om2 = block_sum(v); }

    // ---- precompute y2 and e = <om, x> ----
    dot_rows(make_float4(0.f, 0.f, 0.f, 0.f), y2_s, true);
    {
        float4 om4 = ((const float4*)om_s)[lane];
        dot_rows(om4, e_s, false);
    }

    // ---- Euclidean mean partial ----
    wsum_rows(nullptr, PA + b * PSTR);
    gbar(bar, ++barno * NBLK);

    // ---- init mu (redundant per block) ----
    float mu2;
    {
        reduce128(PA, g_s);
        float m = (t < DDIM) ? g_s[t] * (1.f / NPTS) : 0.f;
        float mn2 = block_sum(m * m);
        float mn = sqrtf(fmaxf(mn2, EPSF));
        float maxn = (1.f - 1e-3f) / sc;
        float f = fminf(1.f, maxn / mn);
        if (t < DDIM) mu_s[t] = m * f;
        float v = (m * f) * (m * f);
        mu2 = block_sum(v);
    }

    // ---- Karcher iterations: 1 barrier each ----
    for (int it = 0; it < FRECHET_ITERS_N; ++it) {
        float* buf = (it & 1) ? PA : PB;
        {
            float4 mu4 = ((const float4*)mu_s)[lane];
            dot_rows(mu4, d_s, false);
        }
        // per-point scalar chain: one THREAD per point (128 parallel chains)
        if (t < PPB) {
            float y2 = y2_s[t], d = d_s[t];
            float P = 1.f - 2.f * c * d;
            float den = fmaxf(P + c * c * mu2 * y2, EPSF);
            float A = -(P + c * y2) / den;
            float B = (1.f - c * mu2) / den;
            float mn2 = fmaxf(A * A * mu2 + 2.f * A * B * d + B * B * y2, EPSF);
            float mn = sqrtf(mn2);
            float tt = atanhf(fminf(sc * mn, TCLIP));
            float s = (fmaxf(1.f - c * mu2, EPSF) / sc) * tt / mn;
            w_s[t] = s * B;
            sA_s[t] = s * A;
        }
        __syncthreads();
        wsum_rows(w_s, buf + b * PSTR);
        float sAv = (t < PPB) ? sA_s[t] : 0.f;
        float sAtot = block_sum(sAv);
        if (t == 0) st_f_sc1(buf + b * PSTR + DDIM, sAtot);
        gbar(bar, ++barno * NBLK);

        // finalize: mu <- expmap(mu, g), redundant per block
        reduce128(buf, g_s);
        float sa = (t < NBLK) ? ld_f_sc1(buf + t * PSTR + DDIM) : 0.f;
        float sAt = block_sum(sa);
        float mu = (t < DDIM) ? mu_s[t] : 0.f;
        float g = (t < DDIM) ? g_s[t] * (1.f / NPTS) + (sAt * (1.f / NPTS)) * mu : 0.f;
        float gn2 = block_sum(g * g);
        float mg  = block_sum(mu * g);
        float un = sqrtf(fmaxf(gn2, EPSF));
        float lam = 2.f / fmaxf(1.f - c * mu2, EPSF);
        float k = tanhf(sc * lam * un * 0.5f) / (sc * un);
        float sec = k * g;
        float ms = k * mg;
        float s2 = k * k * gn2;
        float aa = 1.f + 2.f * c * ms + c * s2;
        float bb2 = 1.f - c * mu2;
        float den = fmaxf(1.f + 2.f * c * ms + c * c * mu2 * s2, EPSF);
        float nmu = (aa * mu + bb2 * sec) / den;
        if (t < DDIM) mu_s[t] = nmu;
        float v2 = (t < DDIM) ? nmu * nmu : 0.f;
        mu2 = block_sum(v2);
    }

    // ---- variance pass (uses buffer NOT written by the last iteration) ----
    float* vbuf = ((FRECHET_ITERS_N - 1) & 1) ? PB : PA;
    {
        float4 mu4 = ((const float4*)mu_s)[lane];
        dot_rows(mu4, d_s, false);   // d_s kept for the output chain
    }
    if (t < PPB) {
        float y2 = y2_s[t], d = d_s[t];
        float P = 1.f - 2.f * c * d;
        float den = fmaxf(P + c * c * mu2 * y2, EPSF);
        float A = -(P + c * y2) / den;
        float B = (1.f - c * mu2) / den;
        float mn2 = fmaxf(A * A * mu2 + 2.f * A * B * d + B * B * y2, EPSF);
        float mn = sqrtf(mn2);
        float tt = atanhf(fminf(sc * mn, TCLIP));
        float dd = (2.f / sc) * tt;
        sA_s[t] = dd * dd;
    }
    __syncthreads();
    {
        float v = (t < PPB) ? sA_s[t] : 0.f;
        float tot = block_sum(v);
        if (t == 0) st_f_sc1(vbuf + b * PSTR + DDIM, tot);
    }
    gbar(bar, ++barno * NBLK);

    float var, gamma;
    {
        float sa = (t < NBLK) ? ld_f_sc1(vbuf + t * PSTR + DDIM) : 0.f;
        var = block_sum(sa) * (1.f / NPTS);
        gamma = sqrtf(var_param[0] / (var + 1e-6f));
    }

    // ---- transport/output scalars (uniform) ----
    float omu;
    {
        float muv = (t < DDIM) ? mu_s[t] : 0.f;
        float omv = (t < DDIM) ? om_s[t] : 0.f;
        omu = block_sum(omv * muv);
    }
    const float Amu = fmaxf(1.f - c * mu2, EPSF);
    const float Aom = fmaxf(1.f - c * om2, EPSF);
    const float ratio = Aom / Amu;           // lam_mu / lam_om
    const float aq = 1.f - 2.f * c * omu + c * mu2;
    const float bq = 1.f - c * om2;
    const float dqv = fmaxf(1.f - 2.f * c * omu + c * c * om2 * mu2, EPSF);
    const float qo = aq / dqv, qm = -bq / dqv;
    const float q2 = qo * qo * om2 + 2.f * qo * qm * omu + qm * qm * mu2;
    const float lam_om = 2.f / Aom;

    // ---- output chain: one thread per point ----
    if (t < PPB) {
        float y2 = y2_s[t], d = d_s[t], e = e_s[t];
        auto dotOm3 = [&](float po, float pm, float px) { return po * om2 + pm * omu + px * e; };
        auto dotMu3 = [&](float po, float pm, float px) { return po * omu + pm * mu2 + px * d; };
        auto sqn3 = [&](float po, float pm, float px) {
            return po * po * om2 + pm * pm * mu2 + px * px * y2
                 + 2.f * (po * pm * omu + po * px * e + pm * px * d);
        };

        // u = logmap(mu, x) = Um*mu + Ux*x
        float P = 1.f - 2.f * c * d;
        float den0 = fmaxf(P + c * c * mu2 * y2, EPSF);
        float A = -(P + c * y2) / den0;
        float B = (1.f - c * mu2) / den0;
        float mn2 = fmaxf(A * A * mu2 + 2.f * A * B * d + B * B * y2, EPSF);
        float mn = sqrtf(mn2);
        float tt = atanhf(fminf(sc * mn, TCLIP));
        float s = (fmaxf(1.f - c * mu2, EPSF) / sc) * tt / mn;
        float Um = s * A, Ux = s * B;

        // h1 = mobius_add(-mu, u)
        float xy1 = -dotMu3(0.f, Um, Ux);
        float Y21 = sqn3(0.f, Um, Ux);
        float a1 = 1.f + 2.f * c * xy1 + c * Y21;
        float b1 = 1.f - c * mu2;
        float dn1 = fmaxf(1.f + 2.f * c * xy1 + c * c * mu2 * Y21, EPSF);
        float h1m = (-a1 + b1 * Um) / dn1;
        float h1x = (b1 * Ux) / dn1;

        // h2 = mobius_add(om, h1)
        float xy2 = dotOm3(0.f, h1m, h1x);
        float Y22 = sqn3(0.f, h1m, h1x);
        float a2 = 1.f + 2.f * c * xy2 + c * Y22;
        float b2 = 1.f - c * om2;
        float dn2 = fmaxf(1.f + 2.f * c * xy2 + c * c * om2 * Y22, EPSF);
        float h2o = a2 / dn2;
        float h2m = (b2 * h1m) / dn2;
        float h2x = (b2 * h1x) / dn2;

        // g2 = mobius_add(-q, h2), q = qo*om + qm*mu
        float xy3 = -(qo * dotOm3(h2o, h2m, h2x) + qm * dotMu3(h2o, h2m, h2x));
        float Y23 = sqn3(h2o, h2m, h2x);
        float a3 = 1.f + 2.f * c * xy3 + c * Y23;
        float b3 = 1.f - c * q2;
        float dn3 = fmaxf(1.f + 2.f * c * xy3 + c * c * q2 * Y23, EPSF);
        float g2o = (-a3 * qo + b3 * h2o) / dn3;
        float g2m = (-a3 * qm + b3 * h2m) / dn3;
        float g2x = (b3 * h2x) / dn3;

        // L = ratio*gamma*g2 ; out = expmap(om, L)
        float k1 = ratio * gamma;
        float Lo = k1 * g2o, Lm = k1 * g2m, Lx = k1 * g2x;
        float un2 = sqn3(Lo, Lm, Lx);
        float un = sqrtf(fmaxf(un2, EPSF));
        float coef = tanhf(sc * lam_om * un * 0.5f) / (sc * un);
        float So = coef * Lo, Sm = coef * Lm, Sx = coef * Lx;
        float xy4 = dotOm3(So, Sm, Sx);
        float Y24 = coef * coef * un2;
        float a4 = 1.f + 2.f * c * xy4 + c * Y24;
        float b4 = 1.f - c * om2;
        float dn4 = fmaxf(1.f + 2.f * c * xy4 + c * c * om2 * Y24, EPSF);
        w_s[t]  = (a4 + b4 * So) / dn4;   // fo
        sA_s[t] = (b4 * Sm) / dn4;        // fm
        fx_s[t] = (b4 * Sx) / dn4;        // fx
    }
    __syncthreads();

    // ---- output store from registers, float4 coalesced ----
    {
        float4 mu4f = ((const float4*)mu_s)[lane];
        float4 om4f = ((const float4*)om_s)[lane];
        #pragma unroll
        for (int i = 0; i < PPW; ++i) {
            int pl = wv * PPW + i;
            float fo = w_s[pl], fm = sA_s[pl], fx = fx_s[pl];
            float4 x4 = xreg[i];
            float4 o4;
            o4.x = fo * om4f.x + fm * mu4f.x + fx * x4.x;
            o4.y = fo * om4f.y + fm * mu4f.y + fx * x4.y;
            o4.z = fo * om4f.z + fm * mu4f.z + fx * x4.z;
            o4.w = fo * om4f.w + fm * mu4f.w + fx * x4.w;
            ((float4*)out)[(p0 + pl) * 64 + lane] = o4;
        }
    }
}

extern "C" void kernel_launch(void* const* d_in, const int* in_sizes, int n_in,
                              void* d_out, int out_size, void* d_ws, size_t ws_size,
                              hipStream_t stream) {
    const float* x = (const float*)d_in[0];
    const float* K = (const float*)d_in[1];
    const float* mean_param = (const float*)d_in[2];
    const float* var_param = (const float*)d_in[3];
    float* out = (float*)d_out;
    float* ws = (float*)d_ws;

    init_bar<<<1, 1, 0, stream>>>(ws);
    void* args[] = {(void*)&x, (void*)&K, (void*)&mean_param, (void*)&var_param,
                    (void*)&out, (void*)&ws};
    hipLaunchCooperativeKernel((const void*)rbn_fused, dim3(NBLK), dim3(NTHR),
                               args, 0, stream);
}